// Round 11
// baseline (240.740 us; speedup 1.0000x reference)
//
#include <hip/hip_runtime.h>
#include <math.h>

#define Kk 8
#define Bb 32
#define Cc 3
#define HW 36864          // 192*192
#define HW4 9216          // float4s per plane
#define CHW 110592        // 3*HW
#define CHW4 27648        // float4s per (k,b) image
#define BCHW 3538944      // B*C*HW
#define OUTMAIN 31850496  // 9*BCHW : index tail start in d_out (elements)
#define NCH 36            // chunks per batch (1024 px each)
#define PARTN 864         // 24*NCH per batch
#define INVVAR 11.11111111111111f
#define EPSf 1e-5f

typedef float v4f __attribute__((ext_vector_type(4)));

__device__ __forceinline__ int clampK(int v) { return v < 0 ? 0 : (v > Kk - 1 ? Kk - 1 : v); }
__device__ __forceinline__ float4 ld4(const float* p) { return *reinterpret_cast<const float4*>(p); }
__device__ __forceinline__ void st4(float* p, float4 v) { *reinterpret_cast<float4*>(p) = v; }

// Untracked async load: compiler cannot insert a waitcnt for this, so 16 of
// them issue back-to-back = guaranteed MLP. MUST be followed by an explicit
// s_waitcnt vmcnt(0) + sched_barrier(0) before any use of the results.
__device__ __forceinline__ v4f ldg4_async(const float* p) {
    v4f r;
    asm volatile("global_load_dwordx4 %0, %1, off" : "=v"(r) : "v"(p));
    return r;
}

// ---------------------------------------------------------------------------
// Kernel 1: recon -> out[0], sd = shp*sum_c(apc-img)^2, and the t=0 reduction
// (P==1) -> partials0. Same math/order as round 10 (bit-exact); loads forced
// into two 16-deep async batches per thread. grid: 1152 x 256.
// ---------------------------------------------------------------------------
__global__ __launch_bounds__(256, 3) void k_pre_red0(
    const float* __restrict__ images, const float* __restrict__ apc,
    const float* __restrict__ shp, const float* __restrict__ zeta,
    const float* __restrict__ back, float* __restrict__ out,
    float* __restrict__ sd, float* __restrict__ partials0)
{
    int tid = threadIdx.x;
    int b = blockIdx.x / NCH, ch = blockIdx.x % NCH;   // HW4 = NCH*256 exactly
    int pix = ch * 1024 + tid * 4;

    float4 img[Cc], bk[Cc], rec[Cc];
#pragma unroll
    for (int c = 0; c < Cc; ++c) {
        img[c] = ld4(images + (size_t)(b * Cc + c) * HW + pix);
        bk[c]  = ld4(back   + (size_t)(b * Cc + c) * HW + pix);
        rec[c] = make_float4(0.f, 0.f, 0.f, 0.f);
    }
    float cum0 = 1.f, cum1 = 1.f, cum2 = 1.f, cum3 = 1.f;
    float acc[24];

#pragma unroll
    for (int half = 0; half < 2; ++half) {
        const int k0 = half * 4;
        // ---- 16 async loads, no compiler waitcnt possible in between ----
        v4f s[4], a[4][Cc];
#pragma unroll
        for (int kk = 0; kk < 4; ++kk)
            s[kk] = ldg4_async(shp + (size_t)((k0 + kk) * Bb + b) * HW + pix);
#pragma unroll
        for (int kk = 0; kk < 4; ++kk)
#pragma unroll
            for (int c = 0; c < Cc; ++c)
                a[kk][c] = ldg4_async(apc + ((size_t)((k0 + kk) * Bb + b) * Cc + c) * HW + pix);
        asm volatile("s_waitcnt vmcnt(0)" ::: "memory");
        __builtin_amdgcn_sched_barrier(0);
        // ---- compute (identical expressions/order to round 10) ----
#pragma unroll
        for (int kk = 0; kk < 4; ++kk) {
            int k = k0 + kk;
            float z = zeta[k * Bb + b];
            float x0 = s[kk].x * z, x1 = s[kk].y * z, x2 = s[kk].z * z, x3 = s[kk].w * z;
            float g0 = x0 * cum0, g1 = x1 * cum1, g2 = x2 * cum2, g3 = x3 * cum3;
            float df0 = 0.f, df1 = 0.f, df2 = 0.f, df3 = 0.f;
#pragma unroll
            for (int c = 0; c < Cc; ++c) {
                v4f av = a[kk][c];
                float d0 = av.x - img[c].x, d1 = av.y - img[c].y;
                float d2 = av.z - img[c].z, d3 = av.w - img[c].w;
                df0 += d0 * d0; df1 += d1 * d1; df2 += d2 * d2; df3 += d3 * d3;
                rec[c].x += g0 * av.x; rec[c].y += g1 * av.y;
                rec[c].z += g2 * av.z; rec[c].w += g3 * av.w;
            }
            float4 sdv = make_float4(s[kk].x * df0, s[kk].y * df1, s[kk].z * df2, s[kk].w * df3);
            st4(sd + (size_t)(k * Bb + b) * HW + pix, sdv);
            acc[3 * k + 0] = (sdv.x + sdv.y) + (sdv.z + sdv.w);
            acc[3 * k + 1] = (s[kk].x + s[kk].y) + (s[kk].z + s[kk].w);
            acc[3 * k + 2] = fmaxf(fmaxf(s[kk].x, s[kk].y), fmaxf(s[kk].z, s[kk].w));
            cum0 *= (1.f - x0); cum1 *= (1.f - x1); cum2 *= (1.f - x2); cum3 *= (1.f - x3);
        }
    }
#pragma unroll
    for (int c = 0; c < Cc; ++c) {
        st4(out + (size_t)(b * Cc + c) * HW + pix,
            make_float4(rec[c].x + cum0 * bk[c].x, rec[c].y + cum1 * bk[c].y,
                        rec[c].z + cum2 * bk[c].z, rec[c].w + cum3 * bk[c].w));
    }

    __shared__ float ls[128][25];
    if (tid >= 128) {
#pragma unroll
        for (int q = 0; q < 24; ++q) ls[tid - 128][q] = acc[q];
    }
    __syncthreads();
    if (tid < 128) {
#pragma unroll
        for (int q = 0; q < 24; ++q) {
            float o = ls[tid][q];
            ls[tid][q] = (q % 3 == 2) ? fmaxf(acc[q], o) : (acc[q] + o);
        }
    }
    __syncthreads();
    for (int st = 64; st > 0; st >>= 1) {
        if (tid < st) {
#pragma unroll
            for (int q = 0; q < 24; ++q) {
                float o = ls[tid + st][q];
                ls[tid][q] = (q % 3 == 2) ? fmaxf(ls[tid][q], o) : (ls[tid][q] + o);
            }
        }
        __syncthreads();
    }
    if (tid < 24) partials0[(size_t)b * PARTN + tid * NCH + ch] = ls[0][tid];
}

// ---------------------------------------------------------------------------
// Kernel 2 (step t = 1..7): unchanged from round 10 (proven; ~6.3 TB/s
// effective = at roofline). grid: 1152 x 256.
// ---------------------------------------------------------------------------
__global__ __launch_bounds__(256, 4) void k_red_fast(
    const float* __restrict__ shp, const float* __restrict__ sd,
    float* __restrict__ Pbuf, float* idxf, const float* __restrict__ zeta,
    const float* __restrict__ partials_prev, float* __restrict__ partials_cur,
    int t)
{
    int b = blockIdx.x / NCH, ch = blockIdx.x % NCH;
    int tid = threadIdx.x;

    __shared__ float svals[24];
    __shared__ int s_sel;
    if (tid < 24) {
        int comp = tid % 3;
        float v = (comp == 2) ? -1e30f : 0.f;
        for (int j = 0; j < NCH; ++j) {
            float x = partials_prev[(size_t)b * PARTN + tid * NCH + j];
            v = (comp == 2) ? fmaxf(v, x) : (v + x);
        }
        svals[tid] = v;
    }
    __syncthreads();
    if (tid == 0) {
        float best = -1e30f; int bi = 0;
        for (int k = 0; k < Kk; ++k) {
            float coef = 1.f;
            for (int j = 0; j < t - 1; ++j)
                if (clampK((int)idxf[j * Bb + b]) == k) coef = -1.f;
            float sc = coef * svals[3 * k + 2] * zeta[k * Bb + b] *
                       expf(-0.5f * INVVAR * svals[3 * k + 0] / (svals[3 * k + 1] + EPSf));
            if (sc > best) { best = sc; bi = k; }
        }
        s_sel = bi;
        if (ch == 0) idxf[(t - 1) * Bb + b] = (float)bi;
    }
    __syncthreads();
    int sel = s_sel;

    int pix = ch * 1024 + tid * 4;

    float4 s[Kk], v[Kk];
#pragma unroll
    for (int k = 0; k < Kk; ++k) s[k] = ld4(shp + (size_t)(k * Bb + b) * HW + pix);
#pragma unroll
    for (int k = 0; k < Kk; ++k) v[k] = ld4(sd + (size_t)(k * Bb + b) * HW + pix);
    float4 sh = ld4(shp + (size_t)(sel * Bb + b) * HW + pix);
    float4 pold = make_float4(1.f, 1.f, 1.f, 1.f);
    if (t > 1) pold = ld4(Pbuf + (size_t)b * HW + pix);

    float P0 = pold.x * (1.f - sh.x * pold.x), P1 = pold.y * (1.f - sh.y * pold.y);
    float P2 = pold.z * (1.f - sh.z * pold.z), P3 = pold.w * (1.f - sh.w * pold.w);
    st4(Pbuf + (size_t)b * HW + pix, make_float4(P0, P1, P2, P3));

    float acc[24];
#pragma unroll
    for (int k = 0; k < Kk; ++k) {
        float m0 = s[k].x * P0, m1 = s[k].y * P1, m2 = s[k].z * P2, m3 = s[k].w * P3;
        acc[3 * k + 0] = (v[k].x * P0 + v[k].y * P1) + (v[k].z * P2 + v[k].w * P3);
        acc[3 * k + 1] = (m0 + m1) + (m2 + m3);
        acc[3 * k + 2] = fmaxf(fmaxf(m0, m1), fmaxf(m2, m3));
    }

    __shared__ float ls[128][25];
    if (tid >= 128) {
#pragma unroll
        for (int q = 0; q < 24; ++q) ls[tid - 128][q] = acc[q];
    }
    __syncthreads();
    if (tid < 128) {
#pragma unroll
        for (int q = 0; q < 24; ++q) {
            float o = ls[tid][q];
            ls[tid][q] = (q % 3 == 2) ? fmaxf(acc[q], o) : (acc[q] + o);
        }
    }
    __syncthreads();
    for (int st = 64; st > 0; st >>= 1) {
        if (tid < st) {
#pragma unroll
            for (int q = 0; q < 24; ++q) {
                float o = ls[tid + st][q];
                ls[tid][q] = (q % 3 == 2) ? fmaxf(ls[tid][q], o) : (ls[tid][q] + o);
            }
        }
        __syncthreads();
    }
    if (tid < 24) partials_cur[(size_t)b * PARTN + tid * NCH + ch] = ls[0][tid];
}

// ---------------------------------------------------------------------------
// Kernel 3: gather with fused final (t=7) argmax. Unchanged from round 10.
// grid: 6912 x 256.
// ---------------------------------------------------------------------------
__global__ __launch_bounds__(256) void k_gather(
    const float* __restrict__ apc, const float* __restrict__ partials7,
    const float* __restrict__ zeta, float* idxf, float* __restrict__ out)
{
    int image = blockIdx.x / 27;           // 0..255 == t*32+b
    int chunk = blockIdx.x % 27;
    int t = image >> 5, b = image & 31;
    int tid = threadIdx.x;

    int s;
    if (t == 7) {
        __shared__ float vals[24];
        __shared__ int s_sel;
        if (tid < 24) {
            int comp = tid % 3;
            float v = (comp == 2) ? -1e30f : 0.f;
            for (int j = 0; j < NCH; ++j) {
                float x = partials7[(size_t)b * PARTN + tid * NCH + j];
                v = (comp == 2) ? fmaxf(v, x) : (v + x);
            }
            vals[tid] = v;
        }
        __syncthreads();
        if (tid == 0) {
            float best = -1e30f; int bi = 0;
            for (int k = 0; k < Kk; ++k) {
                float coef = 1.f;
                for (int j = 0; j < 7; ++j)
                    if (clampK((int)idxf[j * Bb + b]) == k) coef = -1.f;
                float sc = coef * vals[3 * k + 2] * zeta[k * Bb + b] *
                           expf(-0.5f * INVVAR * vals[3 * k + 0] / (vals[3 * k + 1] + EPSf));
                if (sc > best) { best = sc; bi = k; }
            }
            s_sel = bi;
            if (chunk == 0) idxf[7 * Bb + b] = (float)bi;
        }
        __syncthreads();
        s = s_sel;
    } else {
        s = clampK((int)idxf[t * Bb + b]);
    }

    const float4* src = reinterpret_cast<const float4*>(apc) + (size_t)(s * Bb + b) * CHW4;
    float4* dst = reinterpret_cast<float4*>(out) + (size_t)(image + Bb) * CHW4;
    int base = chunk * 1024 + tid;
    float4 r0 = src[base];
    float4 r1 = src[base + 256];
    float4 r2 = src[base + 512];
    float4 r3 = src[base + 768];
    dst[base]       = r0;
    dst[base + 256] = r1;
    dst[base + 512] = r2;
    dst[base + 768] = r3;
}

// ---------------------------------------------------------------------------
// Round 11: k_pre_red0 loads forced to 16-deep async batches via inline-asm
// global_load_dwordx4 (compiler can't insert waits) + explicit vmcnt(0) +
// sched_barrier(0). Everything else byte-identical to round 10 (passed).
// Evidence: VGPR=84 unchanged across r7/r9/r10 -> source-level hoisting was
// re-serialized by the scheduler; pre invariant at ~75-88us across width/
// occupancy/traffic => latency-bound with MLP~4.
// ---------------------------------------------------------------------------
extern "C" void kernel_launch(void* const* d_in, const int* in_sizes, int n_in,
                              void* d_out, int out_size, void* d_ws, size_t ws_size,
                              hipStream_t stream)
{
    const float *images = nullptr, *apc = nullptr, *shp = nullptr;
    const float *zeta = nullptr, *back = nullptr;
    for (int i = 0; i < n_in; ++i) {
        int s = in_sizes[i];
        if (s == 28311552)      apc  = (const float*)d_in[i];
        else if (s == 9437184)  shp  = (const float*)d_in[i];
        else if (s == 256)      zeta = (const float*)d_in[i];
        else if (s == 3538944) {
            if (!images) images = (const float*)d_in[i];
            else         back   = (const float*)d_in[i];
        }
    }
    if (!images || !apc || !shp || !zeta || !back) {   // fallback: dict order
        images = (const float*)d_in[0]; apc = (const float*)d_in[1];
        shp = (const float*)d_in[2]; zeta = (const float*)d_in[3];
        back = (const float*)d_in[4];
    }
    float* out = (float*)d_out;
    float* idxf = out + OUTMAIN;                       // 256-element tail

    // Scratch: sd(9437184) + Pbuf(1179648) + pA(27648) + pB(27648) = 42.7MB
    float* sd = (d_ws != nullptr && ws_size >= (size_t)48 * 1024 * 1024)
                  ? (float*)d_ws
                  : (out + BCHW);    // alias into out[1..8], dead before gather
    float* Pbuf = sd + 9437184;
    float* pA   = Pbuf + 1179648;
    float* pB   = pA + 27648;

    // partials(0) -> pA (red(t) reads (t&1)?pA:pB)
    k_pre_red0<<<1152, 256, 0, stream>>>(images, apc, shp, zeta, back, out, sd, pA);
    for (int t = 1; t < Kk; ++t) {
        float* prev = (t & 1) ? pA : pB;
        float* cur  = (t & 1) ? pB : pA;
        k_red_fast<<<1152, 256, 0, stream>>>(shp, sd, Pbuf, idxf, zeta, prev, cur, t);
    }
    // partials(7): t=7 -> cur = pB
    k_gather<<<6912, 256, 0, stream>>>(apc, pB, zeta, idxf, out);
}

// Round 12
// 217.643 us; speedup vs baseline: 1.1061x; 1.1061x over previous
//
#include <hip/hip_runtime.h>
#include <math.h>

#define Kk 8
#define Bb 32
#define Cc 3
#define HW 36864          // 192*192
#define HW4 9216          // float4s per plane
#define CHW 110592        // 3*HW
#define CHW4 27648        // float4s per (k,b) image
#define BCHW 3538944      // B*C*HW
#define OUTMAIN 31850496  // 9*BCHW : index tail start in d_out (elements)
#define NCH 36            // chunks per batch (1024 px each)
#define QK 27             // per-k partial slots: spec[c][3] (24) + plain[3]
#define PARTN 7776        // 8*QK*NCH per batch
#define INVVAR 11.11111111111111f
#define EPSf 1e-5f

__device__ __forceinline__ int clampK(int v) { return v < 0 ? 0 : (v > Kk - 1 ? Kk - 1 : v); }
__device__ __forceinline__ float4 ld4(const float* p) { return *reinterpret_cast<const float4*>(p); }
__device__ __forceinline__ void st4(float* p, float4 v) { *reinterpret_cast<float4*>(p) = v; }

// ---------------------------------------------------------------------------
// Kernel 1: recon -> out[0] AND sd = shp*sum_c(apc-img)^2  (round-7 body,
// proven 76us floor). grid: 1152 x 256, 1 float4/thread.
// ---------------------------------------------------------------------------
__global__ __launch_bounds__(256) void k_pre_fused(
    const float* __restrict__ images, const float* __restrict__ apc,
    const float* __restrict__ shp, const float* __restrict__ zeta,
    const float* __restrict__ back, float* __restrict__ out,
    float* __restrict__ sd)
{
    int gid = blockIdx.x * 256 + threadIdx.x;
    int b = gid / HW4;
    int pix = (gid - b * HW4) * 4;

    float4 img[Cc], bk[Cc], rec[Cc];
#pragma unroll
    for (int c = 0; c < Cc; ++c) {
        img[c] = ld4(images + (size_t)(b * Cc + c) * HW + pix);
        bk[c]  = ld4(back   + (size_t)(b * Cc + c) * HW + pix);
        rec[c] = make_float4(0.f, 0.f, 0.f, 0.f);
    }
    float cum0 = 1.f, cum1 = 1.f, cum2 = 1.f, cum3 = 1.f;

#pragma unroll
    for (int k = 0; k < Kk; ++k) {
        float4 s = ld4(shp + (size_t)(k * Bb + b) * HW + pix);
        float z = zeta[k * Bb + b];
        float x0 = s.x * z, x1 = s.y * z, x2 = s.z * z, x3 = s.w * z;
        float g0 = x0 * cum0, g1 = x1 * cum1, g2 = x2 * cum2, g3 = x3 * cum3;
        float df0 = 0.f, df1 = 0.f, df2 = 0.f, df3 = 0.f;
#pragma unroll
        for (int c = 0; c < Cc; ++c) {
            float4 av = ld4(apc + ((size_t)(k * Bb + b) * Cc + c) * HW + pix);
            float d0 = av.x - img[c].x, d1 = av.y - img[c].y;
            float d2 = av.z - img[c].z, d3 = av.w - img[c].w;
            df0 += d0 * d0; df1 += d1 * d1; df2 += d2 * d2; df3 += d3 * d3;
            rec[c].x += g0 * av.x; rec[c].y += g1 * av.y;
            rec[c].z += g2 * av.z; rec[c].w += g3 * av.w;
        }
        st4(sd + (size_t)(k * Bb + b) * HW + pix,
            make_float4(s.x * df0, s.y * df1, s.z * df2, s.w * df3));
        cum0 *= (1.f - x0); cum1 *= (1.f - x1); cum2 *= (1.f - x2); cum3 *= (1.f - x3);
    }
#pragma unroll
    for (int c = 0; c < Cc; ++c) {
        st4(out + (size_t)(b * Cc + c) * HW + pix,
            make_float4(rec[c].x + cum0 * bk[c].x, rec[c].y + cum1 * bk[c].y,
                        rec[c].z + cum2 * bk[c].z, rec[c].w + cum3 * bk[c].w));
    }
}

// ---------------------------------------------------------------------------
// Head: resolve idx_{t-2} (plain partials) then idx_{t-1} (spec slice) from
// pprev. Used by k_spec (t=2,4,6) and k_gather (t=8). All blocks compute it
// redundantly (deterministic, same inputs -> same result).
// ---------------------------------------------------------------------------
__device__ __forceinline__ void run_head(
    const float* __restrict__ pprev, const float* __restrict__ zeta,
    float* idxf, int b, int t, int write_idx, int tid,
    float* sv, int* s_ia, int* s_ib, int* s_mask)
{
    // phase 1: plain_{t-2}
    if (tid < 24) {
        int k = tid / 3, comp = tid - k * 3;
        float v = (comp == 2) ? -1e30f : 0.f;
        const float* src = pprev + (size_t)b * PARTN + (size_t)(k * QK + 24 + comp) * NCH;
        for (int j = 0; j < NCH; ++j) {
            float x = src[j];
            v = (comp == 2) ? fmaxf(v, x) : (v + x);
        }
        sv[tid] = v;
    }
    __syncthreads();
    if (tid == 0) {
        float best = -1e30f; int bi = 0;
        for (int k = 0; k < Kk; ++k) {
            float coef = 1.f;
            for (int j = 0; j < t - 2; ++j)
                if (clampK((int)idxf[j * Bb + b]) == k) coef = -1.f;
            float sc = coef * sv[3 * k + 2] * zeta[k * Bb + b] *
                       expf(-0.5f * INVVAR * sv[3 * k + 0] / (sv[3 * k + 1] + EPSf));
            if (sc > best) { best = sc; bi = k; }
        }
        *s_ia = bi;
    }
    __syncthreads();
    int ia = *s_ia;
    // phase 2: spec_{t-1}[ia]
    if (tid < 24) {
        int k = tid / 3, comp = tid - k * 3;
        float v = (comp == 2) ? -1e30f : 0.f;
        const float* src = pprev + (size_t)b * PARTN + (size_t)(k * QK + ia * 3 + comp) * NCH;
        for (int j = 0; j < NCH; ++j) {
            float x = src[j];
            v = (comp == 2) ? fmaxf(v, x) : (v + x);
        }
        sv[tid] = v;
    }
    __syncthreads();
    if (tid == 0) {
        float best = -1e30f; int bi = 0;
        for (int k = 0; k < Kk; ++k) {
            float coef = 1.f;
            for (int j = 0; j < t - 2; ++j)
                if (clampK((int)idxf[j * Bb + b]) == k) coef = -1.f;
            if (ia == k) coef = -1.f;
            float sc = coef * sv[3 * k + 2] * zeta[k * Bb + b] *
                       expf(-0.5f * INVVAR * sv[3 * k + 0] / (sv[3 * k + 1] + EPSf));
            if (sc > best) { best = sc; bi = k; }
        }
        *s_ib = bi;
        int mask = 0xFF;
        for (int j = 0; j < t - 2; ++j) mask &= ~(1 << clampK((int)idxf[j * Bb + b]));
        mask &= ~(1 << ia); mask &= ~(1 << bi);
        *s_mask = mask;
        if (write_idx) {
            idxf[(t - 2) * Bb + b] = (float)ia;
            idxf[(t - 1) * Bb + b] = (float)bi;
        }
    }
    __syncthreads();
}

// ---------------------------------------------------------------------------
// Kernel 2 (t=0,2,4,6): head resolves idx_{t-2},idx_{t-1}; body computes
// plain_t partials AND speculative step-(t+1) partials for all unselected
// candidates c: weights u_c = 1 - s_c*P_t. Thread split: g=tid>>5 owns k=g,
// 32 px/thread over the block's 1024-px chunk. grid: 1152 x 256.
// partials: [b][k*27 + (c*3+comp | 24..26 plain)][ch]
// ---------------------------------------------------------------------------
__global__ __launch_bounds__(256, 4) void k_spec(
    const float* __restrict__ shp, const float* __restrict__ sd,
    float* __restrict__ Pbuf, float* idxf, const float* __restrict__ zeta,
    const float* __restrict__ pprev, float* __restrict__ pcur, int t)
{
    int b = blockIdx.x / NCH, ch = blockIdx.x % NCH;
    int tid = threadIdx.x;
    int g = tid >> 5, l = tid & 31;

    __shared__ float sv[24];
    __shared__ int s_ia, s_ib, s_mask;

    if (t == 0) {
        if (tid == 0) { s_ia = 0; s_ib = 0; s_mask = 0xFF; }
        __syncthreads();
    } else {
        run_head(pprev, zeta, idxf, b, t, (ch == 0), tid, sv, &s_ia, &s_ib, &s_mask);
    }
    int ia = s_ia, ib = s_ib, mask = s_mask;

    float pd = 0.f, pa = 0.f, pm = -1e30f;
    float accd[Kk], acca[Kk], accm[Kk];
#pragma unroll
    for (int c = 0; c < Kk; ++c) { accd[c] = 0.f; acca[c] = 0.f; accm[c] = -1e30f; }

    const size_t bHW = (size_t)b * HW;
    for (int i = 0; i < 8; ++i) {
        int px = ch * 1024 + (i * 32 + l) * 4;
        float4 sc0 = ld4(shp + (size_t)(0 * Bb + b) * HW + px);
        float4 sc1 = ld4(shp + (size_t)(1 * Bb + b) * HW + px);
        float4 sc2 = ld4(shp + (size_t)(2 * Bb + b) * HW + px);
        float4 sc3 = ld4(shp + (size_t)(3 * Bb + b) * HW + px);
        float4 sc4 = ld4(shp + (size_t)(4 * Bb + b) * HW + px);
        float4 sc5 = ld4(shp + (size_t)(5 * Bb + b) * HW + px);
        float4 sc6 = ld4(shp + (size_t)(6 * Bb + b) * HW + px);
        float4 sc7 = ld4(shp + (size_t)(7 * Bb + b) * HW + px);
        float4 sdg = ld4(sd  + (size_t)(g * Bb + b) * HW + px);
        float4 sg  = ld4(shp + (size_t)(g * Bb + b) * HW + px);   // L1 hit

        float4 P;
        if (t == 0) {
            P = make_float4(1.f, 1.f, 1.f, 1.f);
        } else {
            float4 p0 = make_float4(1.f, 1.f, 1.f, 1.f);
            if (t > 2) p0 = ld4(Pbuf + bHW + px);
            float4 sa = ld4(shp + (size_t)(ia * Bb + b) * HW + px);  // L1 hit
            float4 sb = ld4(shp + (size_t)(ib * Bb + b) * HW + px);  // L1 hit
            float4 p1;
            p1.x = p0.x * (1.f - sa.x * p0.x); p1.y = p0.y * (1.f - sa.y * p0.y);
            p1.z = p0.z * (1.f - sa.z * p0.z); p1.w = p0.w * (1.f - sa.w * p0.w);
            P.x = p1.x * (1.f - sb.x * p1.x); P.y = p1.y * (1.f - sb.y * p1.y);
            P.z = p1.z * (1.f - sb.z * p1.z); P.w = p1.w * (1.f - sb.w * p1.w);
            if ((t == 2 || t == 4) && g == 0) st4(Pbuf + bHW + px, P);
        }

#define SPEC_C(c, scv) if (mask & (1 << c)) { \
        float u = 1.f - scv * P_; float tt = m_ * u; \
        acca[c] += tt; accm[c] = fmaxf(accm[c], tt); accd[c] = fmaf(v_, u, accd[c]); }
#define DO_ELEM(e) { float P_ = P.e; float m_ = sg.e * P_; float v_ = sdg.e * P_; \
        pd += v_; pa += m_; pm = fmaxf(pm, m_); \
        SPEC_C(0, sc0.e) SPEC_C(1, sc1.e) SPEC_C(2, sc2.e) SPEC_C(3, sc3.e) \
        SPEC_C(4, sc4.e) SPEC_C(5, sc5.e) SPEC_C(6, sc6.e) SPEC_C(7, sc7.e) }
        DO_ELEM(x) DO_ELEM(y) DO_ELEM(z) DO_ELEM(w)
#undef DO_ELEM
#undef SPEC_C
    }

    // LDS reduce: per k-group (32 lanes), 27 values. stride 29 (coprime 32).
    __shared__ float ls[8][32][29];
    float* mine = ls[g][l];
#pragma unroll
    for (int c = 0; c < Kk; ++c) {
        mine[c * 3 + 0] = accd[c]; mine[c * 3 + 1] = acca[c]; mine[c * 3 + 2] = accm[c];
    }
    mine[24] = pd; mine[25] = pa; mine[26] = pm;
    __syncthreads();
    for (int st = 16; st > 0; st >>= 1) {
        if (l < st) {
            float* other = ls[g][l + st];
#pragma unroll
            for (int q = 0; q < QK; ++q)
                mine[q] = (q % 3 == 2) ? fmaxf(mine[q], other[q]) : (mine[q] + other[q]);
        }
        __syncthreads();
    }
    if (l == 0) {
#pragma unroll
        for (int q = 0; q < QK; ++q)
            pcur[(size_t)b * PARTN + (size_t)(g * QK + q) * NCH + ch] = mine[q];
    }
}

// ---------------------------------------------------------------------------
// Kernel 3: out[1+t] = apc[idx[t]] (4 float4/thread). Blocks with t>=6 run
// the head on D6's partials to resolve idx6/idx7 (t==6 chunk==0 writes both).
// grid: 6912 x 256.
// ---------------------------------------------------------------------------
__global__ __launch_bounds__(256) void k_gather(
    const float* __restrict__ apc, const float* __restrict__ partials6,
    const float* __restrict__ zeta, float* idxf, float* __restrict__ out)
{
    int image = blockIdx.x / 27;           // 0..255 == t*32+b
    int chunk = blockIdx.x % 27;
    int t = image >> 5, b = image & 31;
    int tid = threadIdx.x;

    int s;
    if (t >= 6) {
        __shared__ float sv[24];
        __shared__ int s_ia, s_ib, s_mask;
        run_head(partials6, zeta, idxf, b, 8, (t == 6 && chunk == 0), tid,
                 sv, &s_ia, &s_ib, &s_mask);
        s = (t == 6) ? s_ia : s_ib;
    } else {
        s = clampK((int)idxf[t * Bb + b]);
    }

    const float4* src = reinterpret_cast<const float4*>(apc) + (size_t)(s * Bb + b) * CHW4;
    float4* dst = reinterpret_cast<float4*>(out) + (size_t)(image + Bb) * CHW4;
    int base = chunk * 1024 + tid;
    float4 r0 = src[base];
    float4 r1 = src[base + 256];
    float4 r2 = src[base + 512];
    float4 r3 = src[base + 768];
    dst[base]       = r0;
    dst[base + 256] = r1;
    dst[base + 512] = r2;
    dst[base + 768] = r3;
}

// ---------------------------------------------------------------------------
// Round 12: speculative 2-steps-per-kernel. Each k_spec computes plain step-t
// partials + step-(t+1) partials for all candidate winners c (u=1-s_c*P in
// the same pass) -> 8 reduction kernels become 4 (D0,D2,D4,D6). Heads resolve
// two indices from the previous kernel's partials. pre reverted to round-7
// body (76us floor; r10 fusion was net-neutral and r11 asm was worse).
// 6 launches total. No shuffles.
// ---------------------------------------------------------------------------
extern "C" void kernel_launch(void* const* d_in, const int* in_sizes, int n_in,
                              void* d_out, int out_size, void* d_ws, size_t ws_size,
                              hipStream_t stream)
{
    const float *images = nullptr, *apc = nullptr, *shp = nullptr;
    const float *zeta = nullptr, *back = nullptr;
    for (int i = 0; i < n_in; ++i) {
        int s = in_sizes[i];
        if (s == 28311552)      apc  = (const float*)d_in[i];
        else if (s == 9437184)  shp  = (const float*)d_in[i];
        else if (s == 256)      zeta = (const float*)d_in[i];
        else if (s == 3538944) {
            if (!images) images = (const float*)d_in[i];
            else         back   = (const float*)d_in[i];
        }
    }
    if (!images || !apc || !shp || !zeta || !back) {   // fallback: dict order
        images = (const float*)d_in[0]; apc = (const float*)d_in[1];
        shp = (const float*)d_in[2]; zeta = (const float*)d_in[3];
        back = (const float*)d_in[4];
    }
    float* out = (float*)d_out;
    float* idxf = out + OUTMAIN;                       // 256-element tail

    // Scratch: sd(9437184) + Pbuf(1179648) + pA(248832) + pB(248832) = 44.5MB
    float* sd = (d_ws != nullptr && ws_size >= (size_t)48 * 1024 * 1024)
                  ? (float*)d_ws
                  : (out + BCHW);    // alias into out[1..8], dead before gather
    float* Pbuf = sd + 9437184;
    float* pA   = Pbuf + 1179648;
    float* pB   = pA + 248832;

    k_pre_fused<<<1152, 256, 0, stream>>>(images, apc, shp, zeta, back, out, sd);
    k_spec<<<1152, 256, 0, stream>>>(shp, sd, Pbuf, idxf, zeta, pB, pA, 0);
    k_spec<<<1152, 256, 0, stream>>>(shp, sd, Pbuf, idxf, zeta, pA, pB, 2);
    k_spec<<<1152, 256, 0, stream>>>(shp, sd, Pbuf, idxf, zeta, pB, pA, 4);
    k_spec<<<1152, 256, 0, stream>>>(shp, sd, Pbuf, idxf, zeta, pA, pB, 6);
    k_gather<<<6912, 256, 0, stream>>>(apc, pB, zeta, idxf, out);
}